// Round 2
// baseline (756.087 us; speedup 1.0000x reference)
//
#include <hip/hip_runtime.h>
#include <hip/hip_bf16.h>
#include <cstdint>
#include <cstddef>

using bf16 = __hip_bfloat16;
typedef __bf16 bf16x8 __attribute__((ext_vector_type(8)));
typedef float floatx4 __attribute__((ext_vector_type(4)));

#define B_  2
#define T_  4096
#define C_  2048
#define H_  16
#define HK_ 8
#define D_  128
#define W_  512
#define BT_ (B_*T_)

__device__ __forceinline__ void gload_lds16(const void* g, void* l) {
  __builtin_amdgcn_global_load_lds((const __attribute__((address_space(1))) void*)g,
                                   (__attribute__((address_space(3))) void*)l, 16, 0, 0);
}
__device__ __forceinline__ floatx4 mfma16(bf16x8 a, bf16x8 b, floatx4 c) {
  return __builtin_amdgcn_mfma_f32_16x16x32_bf16(a, b, c, 0, 0, 0);
}
__device__ __forceinline__ __bf16 f2b(float f) {
  union { bf16 h; __bf16 b; } u; u.h = __float2bfloat16(f); return u.b;
}
__device__ __forceinline__ bf16x8 load8(const bf16* p) {
  return *(const bf16x8*)(const void*)p;
}
__device__ __forceinline__ bf16x8 load8(const float* p) {
  float4 a = *(const float4*)(const void*)p;
  float4 b = *(const float4*)(const void*)(p + 4);
  bf16x8 r;
  r[0]=f2b(a.x); r[1]=f2b(a.y); r[2]=f2b(a.z); r[3]=f2b(a.w);
  r[4]=f2b(b.x); r[5]=f2b(b.y); r[6]=f2b(b.z); r[7]=f2b(b.w);
  return r;
}
__device__ __forceinline__ void store1(float* p, float v) { *p = v; }
__device__ __forceinline__ void store1(bf16*  p, float v) { *p = __float2bfloat16(v); }

// One-shot f32 -> bf16 conversion of x and the four weight matrices.
__global__ __launch_bounds__(256) void cvt_k(const float* __restrict__ x,
                                             const float* __restrict__ wq,
                                             const float* __restrict__ wk,
                                             const float* __restrict__ wv,
                                             const float* __restrict__ wproj,
                                             bf16* __restrict__ xb,
                                             bf16* __restrict__ wqb,
                                             bf16* __restrict__ wkb,
                                             bf16* __restrict__ wvb,
                                             bf16* __restrict__ wprojb) {
  const int b = blockIdx.x;
  const float* src; bf16* dst; size_t off;
  if (b < 8192)       { src = x;     dst = xb;     off = (size_t)b * 2048; }
  else if (b < 10240) { src = wq;    dst = wqb;    off = (size_t)(b-8192) * 2048; }
  else if (b < 11264) { src = wk;    dst = wkb;    off = (size_t)(b-10240) * 2048; }
  else if (b < 12288) { src = wv;    dst = wvb;    off = (size_t)(b-11264) * 2048; }
  else                { src = wproj; dst = wprojb; off = (size_t)(b-12288) * 2048; }
  const size_t i = off + (size_t)threadIdx.x * 8;
  *(bf16x8*)(void*)(dst + i) = load8(src + i);
}

// C[m][n] = sum_k A[m][k] * B[n][k], all-bf16 inputs, m97-style DMA staging.
template<typename TC>
__global__ __launch_bounds__(256) void gemm_bt(const bf16* __restrict__ A,
                                               const bf16* __restrict__ Bw,
                                               TC* __restrict__ Cc,
                                               int M, int N, int Kd) {
  __shared__ alignas(16) bf16 As[128*64];
  __shared__ alignas(16) bf16 Bs[128*64];
  const int tid = threadIdx.x;
  const int w = tid >> 6, lane = tid & 63;
  const int quad = lane >> 4, l16 = lane & 15;
  const int wm = (w & 1) * 64, wn = (w >> 1) * 64;
  const int m0 = blockIdx.y * 128, n0 = blockIdx.x * 128;
  const int srow = lane >> 3, sseg = lane & 7;

  floatx4 acc[4][4];
  #pragma unroll
  for (int i = 0; i < 4; ++i)
    #pragma unroll
    for (int j = 0; j < 4; ++j) acc[i][j] = (floatx4){0.f, 0.f, 0.f, 0.f};

  for (int k0 = 0; k0 < Kd; k0 += 64) {
    __syncthreads();
    #pragma unroll
    for (int i = 0; i < 4; ++i) {
      const int r  = w*32 + i*8 + srow;
      const int gs = (sseg ^ (r & 7)) * 8;
      gload_lds16(A  + (size_t)(m0 + r)*Kd + k0 + gs, As + (w*32 + i*8)*64);
      gload_lds16(Bw + (size_t)(n0 + r)*Kd + k0 + gs, Bs + (w*32 + i*8)*64);
    }
    __syncthreads();
    #pragma unroll
    for (int kk = 0; kk < 2; ++kk) {
      bf16x8 af[4], bfr[4];
      #pragma unroll
      for (int mt = 0; mt < 4; ++mt) {
        const int m = wm + mt*16 + l16;
        af[mt] = load8(As + m*64 + (((kk*4 + quad) ^ (m & 7)) * 8));
      }
      #pragma unroll
      for (int nt = 0; nt < 4; ++nt) {
        const int n = wn + nt*16 + l16;
        bfr[nt] = load8(Bs + n*64 + (((kk*4 + quad) ^ (n & 7)) * 8));
      }
      #pragma unroll
      for (int mt = 0; mt < 4; ++mt)
        #pragma unroll
        for (int nt = 0; nt < 4; ++nt)
          acc[mt][nt] = mfma16(af[mt], bfr[nt], acc[mt][nt]);
    }
  }

  #pragma unroll
  for (int mt = 0; mt < 4; ++mt)
    #pragma unroll
    for (int r = 0; r < 4; ++r) {
      const size_t row = (size_t)(m0 + wm + mt*16 + quad*4 + r);
      #pragma unroll
      for (int nt = 0; nt < 4; ++nt) {
        const int col = n0 + wn + nt*16 + l16;
        store1(Cc + row*N + col, acc[mt][nt][r]);
      }
    }
}

// grid (BT, 32), block 128.
__global__ __launch_bounds__(128) void fuse_k(const float* __restrict__ x,
                                              const float* __restrict__ ve,
                                              const float* __restrict__ cosb,
                                              const float* __restrict__ sinb,
                                              const float* __restrict__ wgate,
                                              bf16* __restrict__ Q,
                                              bf16* __restrict__ Kw,
                                              bf16* __restrict__ Vw) {
  const int tok = blockIdx.x;
  const int j   = blockIdx.y;
  const int t   = tok & (T_ - 1);
  const int tid = threadIdx.x;

  if (j < 24) {
    bf16* base = (j < 16) ? (Q + (size_t)tok * C_ + j * D_)
                          : (Kw + (size_t)tok * (HK_*D_) + (j - 16) * D_);
    const int d  = tid;
    const float v0 = __bfloat162float(base[d]);
    const float vp = __bfloat162float(base[d ^ 64]);
    const int dd = d & 63;
    const float c = cosb[t*64 + dd];
    const float s = sinb[t*64 + dd];
    const float val = (d < 64) ? (v0*c + vp*s) : (v0*c - vp*s);
    float ss = val * val;
    #pragma unroll
    for (int off = 1; off < 64; off <<= 1) ss += __shfl_xor(ss, off);
    __shared__ float red[2];
    if ((tid & 63) == 0) red[tid >> 6] = ss;
    __syncthreads();
    const float tot = red[0] + red[1];
    const float sc = rsqrtf(tot * (1.0f/128.0f) + 1.1920929e-7f);
    base[d] = __float2bfloat16(val * sc);
  } else {
    const int hk = j - 24;
    float z = 0.f;
    #pragma unroll
    for (int c = 0; c < 32; ++c)
      z += x[(size_t)tok * C_ + c] * wgate[hk*32 + c];
    const float gate = 2.0f / (1.0f + __expf(-z));
    const size_t idx = (size_t)tok * (HK_*D_) + hk * D_ + tid;
    Vw[idx] = __float2bfloat16(__bfloat162float(Vw[idx]) + gate * ve[idx]);
  }
}

// ---- attention helpers ---------------------------------------------------
// QK^T + online softmax for one 32-key half of a 64-key tile.
// Values in log2 domain (scale folded with log2(e)); defer-max (T13, THR=8).
template<bool MASKED>
__device__ __forceinline__ void half_qk(const int krow0, const int kgbase,
                                        const int q0, const int quad, const int l16,
                                        const bf16x8 (&qf)[2][4],
                                        const bf16* Ks, bf16* Psw,
                                        floatx4 (&o)[2][8],
                                        float (&mr)[2][4], float (&lr)[2][4]) {
  floatx4 s2[2][2];
  s2[0][0] = (floatx4){0.f,0.f,0.f,0.f}; s2[0][1] = (floatx4){0.f,0.f,0.f,0.f};
  s2[1][0] = (floatx4){0.f,0.f,0.f,0.f}; s2[1][1] = (floatx4){0.f,0.f,0.f,0.f};
  #pragma unroll
  for (int kc = 0; kc < 4; ++kc) {
    const int c8 = kc*4 + quad;
    const int sseg = (c8 & 8) | ((c8 ^ (l16 & 7)) & 7);
    bf16x8 bk0 = load8(Ks + (krow0 + l16)*128 + sseg*8);
    bf16x8 bk1 = load8(Ks + (krow0 + 16 + l16)*128 + sseg*8);
    s2[0][0] = mfma16(qf[0][kc], bk0, s2[0][0]);
    s2[0][1] = mfma16(qf[0][kc], bk1, s2[0][1]);
    s2[1][0] = mfma16(qf[1][kc], bk0, s2[1][0]);
    s2[1][1] = mfma16(qf[1][kc], bk1, s2[1][1]);
  }
  const float scale2 = 0.12751744f;  // (1/sqrt(128)) * log2(e)
  #pragma unroll
  for (int mt = 0; mt < 2; ++mt) {
    #pragma unroll
    for (int r = 0; r < 4; ++r) {
      float sv0, sv1;
      if (MASKED) {
        const int qg  = q0 + mt*16 + quad*4 + r;
        const int kg0 = kgbase + l16, kg1 = kgbase + 16 + l16;
        sv0 = (kg0 <= qg && kg0 + W_ >= qg) ? s2[mt][0][r]*scale2 : -3.0e38f;
        sv1 = (kg1 <= qg && kg1 + W_ >= qg) ? s2[mt][1][r]*scale2 : -3.0e38f;
      } else {
        sv0 = s2[mt][0][r]*scale2;
        sv1 = s2[mt][1][r]*scale2;
      }
      float mx = fmaxf(sv0, sv1);
      #pragma unroll
      for (int off = 1; off < 16; off <<= 1) mx = fmaxf(mx, __shfl_xor(mx, off));
      // defer-max: skip O/l rescale unless some row's max grew by > 8 (log2)
      if (!__all(mx <= mr[mt][r] + 8.0f)) {
        const float mnew  = fmaxf(mr[mt][r], mx);
        const float alpha = exp2f(mr[mt][r] - mnew);
        mr[mt][r] = mnew;
        lr[mt][r] *= alpha;
        #pragma unroll
        for (int nt = 0; nt < 8; ++nt) o[mt][nt][r] *= alpha;
      }
      const float p0 = exp2f(sv0 - mr[mt][r]);
      const float p1 = exp2f(sv1 - mr[mt][r]);
      lr[mt][r] += p0 + p1;               // per-lane partial; reduced at epilogue
      const int row = mt*16 + quad*4 + r;
      Psw[row*40 + l16]      = __float2bfloat16(p0);
      Psw[row*40 + 16 + l16] = __float2bfloat16(p1);
    }
  }
}

// P x V for one 32-key half; V read from padded transposed Vt[128][72]
// (round-0-proven layout, extended to 64 keys with a 3-bit XOR block swizzle).
__device__ __forceinline__ void pv_half(const int kh, const int quad, const int l16,
                                        const bf16* Psw, const bf16* Vt,
                                        floatx4 (&o)[2][8]) {
  bf16x8 pa0 = load8(Psw + l16*40 + quad*8);
  bf16x8 pa1 = load8(Psw + (16 + l16)*40 + quad*8);
  #pragma unroll
  for (int nt = 0; nt < 8; ++nt) {
    const int d   = nt*16 + l16;
    const int blk = (kh*4 + quad) ^ ((d >> 3) & 7);
    bf16x8 bv = load8(Vt + d*72 + blk*8);
    o[0][nt] = mfma16(pa0, bv, o[0][nt]);
    o[1][nt] = mfma16(pa1, bv, o[1][nt]);
  }
}

// Flash-style windowed attention. grid (T/128, H, B), block 256 (4 waves).
// KVBLK=64: 2 barriers per 64 keys; K staged by DMA (global_load_lds, image
// identical to the proven register path); V via register transpose.
// LDS: Ks 16K + Vt 18K + Ps 10K = 44 KB.
__global__ __launch_bounds__(256) void attn_k(const bf16* Q,
                                              const bf16* __restrict__ K,
                                              const bf16* __restrict__ V,
                                              bf16* Y) {
  const int t0 = blockIdx.x * 128;
  const int h  = blockIdx.y, bb = blockIdx.z, hk = h >> 1;
  const int tid = threadIdx.x, w = tid >> 6, lane = tid & 63;
  const int quad = lane >> 4, l16 = lane & 15;
  const int q0 = t0 + w * 32;

  __shared__ alignas(16) bf16 Ks[64*128];   // [key][128], seg-XOR swizzled
  __shared__ alignas(16) bf16 Vt[128*72];   // [d][key] transposed, +8 pad, blk-XOR
  __shared__ alignas(16) bf16 Ps[4][32*40]; // per-wave P half-tile, stride 40
  bf16* Psw = Ps[w];

  bf16x8 qf[2][4];
  #pragma unroll
  for (int mt = 0; mt < 2; ++mt)
    #pragma unroll
    for (int kc = 0; kc < 4; ++kc)
      qf[mt][kc] = load8(Q + (size_t)(bb*T_ + q0 + mt*16 + l16)*C_ + h*D_ + kc*32 + quad*8);

  floatx4 o[2][8];
  #pragma unroll
  for (int mt = 0; mt < 2; ++mt)
    #pragma unroll
    for (int nt = 0; nt < 8; ++nt) o[mt][nt] = (floatx4){0.f, 0.f, 0.f, 0.f};
  float mr[2][4], lr[2][4];
  #pragma unroll
  for (int mt = 0; mt < 2; ++mt)
    #pragma unroll
    for (int r = 0; r < 4; ++r) { mr[mt][r] = -1.0e30f; lr[mt][r] = 0.f; }

  const int krow_in = lane >> 4;             // 0..3 (K staging row-in-group)
  const int kseg    = lane & 15;             // K staging LDS 16B seg

  const int kb0 = (t0 >= W_) ? (t0 - W_) : 0;
  for (int kb = kb0; kb < t0 + 128; kb += 64) {
    __syncthreads();
    // K: async DMA into seg-swizzled [key][128] (per-lane pre-swizzled source)
    #pragma unroll
    for (int i = 0; i < 4; ++i) {
      const int g = w*4 + i;
      const int krow = g*4 + krow_in;
      const int gseg = (kseg & 8) | ((kseg ^ (krow & 7)) & 7);
      gload_lds16(K + (size_t)(bb*T_ + kb + krow)*(HK_*D_) + hk*D_ + gseg*8,
                  Ks + g*512);
    }
    // V: register transpose into Vt[d][col], col = ((key>>3)^(d>>3 &7))*8+(key&7)
    #pragma unroll
    for (int jj = 0; jj < 4; ++jj) {
      const int idx = jj*256 + tid;          // 0..1023
      const int key = idx >> 4, seg = idx & 15;
      union { bf16x8 v; bf16 hv[8]; } tmp;
      tmp.v = load8(V + (size_t)(bb*T_ + kb + key)*(HK_*D_) + hk*D_ + seg*8);
      const int colb = ((key >> 3) ^ (seg & 7)) * 8 + (key & 7);
      #pragma unroll
      for (int e = 0; e < 8; ++e)
        Vt[(seg*8 + e)*72 + colb] = tmp.hv[e];
    }
    __syncthreads();

    const bool full = (kb + 63 <= t0) && (kb + W_ >= t0 + 127);
    if (full) {
      half_qk<false>(0,  kb,      q0, quad, l16, qf, Ks, Psw, o, mr, lr);
      pv_half(0, quad, l16, Psw, Vt, o);
      half_qk<false>(32, kb + 32, q0, quad, l16, qf, Ks, Psw, o, mr, lr);
      pv_half(1, quad, l16, Psw, Vt, o);
    } else {
      half_qk<true>(0,  kb,      q0, quad, l16, qf, Ks, Psw, o, mr, lr);
      pv_half(0, quad, l16, Psw, Vt, o);
      half_qk<true>(32, kb + 32, q0, quad, l16, qf, Ks, Psw, o, mr, lr);
      pv_half(1, quad, l16, Psw, Vt, o);
    }
  }

  #pragma unroll
  for (int mt = 0; mt < 2; ++mt)
    #pragma unroll
    for (int r = 0; r < 4; ++r) {
      float lt = lr[mt][r];
      #pragma unroll
      for (int off = 1; off < 16; off <<= 1) lt += __shfl_xor(lt, off);
      const float inv = 1.0f / lt;
      const size_t rowoff = (size_t)(bb*T_ + q0 + mt*16 + quad*4 + r) * C_ + h*D_;
      #pragma unroll
      for (int nt = 0; nt < 8; ++nt)
        Y[rowoff + nt*16 + l16] = __float2bfloat16(o[mt][nt][r] * inv);
    }
}

extern "C" void kernel_launch(void* const* d_in, const int* in_sizes, int n_in,
                              void* d_out, int out_size, void* d_ws, size_t ws_size,
                              hipStream_t stream) {
  (void)in_sizes; (void)n_in; (void)out_size; (void)ws_size;
  const float* x     = (const float*)d_in[0];
  const float* ve    = (const float*)d_in[1];
  const float* cosb  = (const float*)d_in[2];
  const float* sinb  = (const float*)d_in[3];
  const float* wq    = (const float*)d_in[4];
  const float* wk    = (const float*)d_in[5];
  const float* wv    = (const float*)d_in[6];
  const float* wproj = (const float*)d_in[7];
  const float* wgate = (const float*)d_in[8];

  // ws layout (75.5 MB): Q | Kw | Vw | wprojb
  bf16* Q      = (bf16*)d_ws;
  bf16* Kw     = Q  + (size_t)BT_ * C_;
  bf16* Vw     = Kw + (size_t)BT_ * (HK_*D_);
  bf16* wprojb = Vw + (size_t)BT_ * (HK_*D_);

  // Transient bf16 copies live INSIDE d_out (f32): dead before final GEMM.
  bf16* xb  = (bf16*)d_out;
  bf16* wqb = xb  + (size_t)BT_ * C_;
  bf16* wkb = wqb + (size_t)C_ * C_;
  bf16* wvb = wkb + (size_t)(HK_*D_) * C_;

  cvt_k<<<14336, 256, 0, stream>>>(x, wq, wk, wv, wproj, xb, wqb, wkb, wvb, wprojb);
  gemm_bt<bf16><<<dim3(C_/128,       BT_/128), 256, 0, stream>>>(xb, wqb, Q,  BT_, C_,     C_);
  gemm_bt<bf16><<<dim3((HK_*D_)/128, BT_/128), 256, 0, stream>>>(xb, wkb, Kw, BT_, HK_*D_, C_);
  gemm_bt<bf16><<<dim3((HK_*D_)/128, BT_/128), 256, 0, stream>>>(xb, wvb, Vw, BT_, HK_*D_, C_);
  fuse_k<<<dim3(BT_, 32), 128, 0, stream>>>(x, ve, cosb, sinb, wgate, Q, Kw, Vw);
  attn_k<<<dim3(T_/128, H_, B_), 256, 0, stream>>>(Q, Kw, Vw, Q /*Y in-place*/);
  gemm_bt<float><<<dim3(C_/128, BT_/128), 256, 0, stream>>>(Q, wprojb, (float*)d_out, BT_, C_, C_);
}